// Round 2
// baseline (1284.520 us; speedup 1.0000x reference)
//
#include <hip/hip_runtime.h>
#include <hip/hip_bf16.h>
#include <math.h>

// ---------------------------------------------------------------------------
// BRF spiking RNN forward (SimpleResRNNTbptt), MI355X / gfx950
//   T=1000, B=256, I=700, H=256, O=20
// Pipeline:
//   1) prep_kernel:   WhB  = bf16(W_h[:, :700]) padded to 704 cols
//                     WrT[j,h] = W_h[h, 700+j]          (f32, recurrent weights^T)
//   2) gemm_xw:       Xc[t,b,h] = x[t,b,:] @ W_h[h,:700]  (bf16 MFMA -> ws, bf16)
//   3) scan_kernel:   wave-per-batch, 4 units/lane; ballot-only spike exchange
//                     (no LDS, no barriers in the 1000-step loop)
//   4) loss_kernel:   per-(t,b) log-softmax loss from outputs, block-reduce per t
//   5) loss_reduce:   sum 1000 f64 partials / B -> total_loss
// ---------------------------------------------------------------------------

#define T_STEPS 1000
#define BATCH   256
#define NIN     700
#define NH      256
#define NOUT    20
#define LDWH    956   // I + H
#define LDWB    704   // bf16 Wh leading dim (22 * 32, zero-padded 700..703)

typedef __attribute__((ext_vector_type(8))) short short8v;
typedef __attribute__((ext_vector_type(4))) float f32x4;

__device__ __forceinline__ unsigned short f2bf(float f) {
  union { float f; unsigned u; } x; x.f = f;
  unsigned r = x.u + 0x7FFFu + ((x.u >> 16) & 1u);   // RNE
  return (unsigned short)(r >> 16);
}
__device__ __forceinline__ float bf2f(unsigned short s) {
  union { unsigned u; float f; } x; x.u = ((unsigned)s) << 16;
  return x.f;
}

// ---------------------------------------------------------------------------
// prep: WhB (bf16, padded) + WrT (f32 transpose of recurrent block)
// ---------------------------------------------------------------------------
__global__ __launch_bounds__(256) void prep_kernel(
    const float* __restrict__ Wh,
    unsigned short* __restrict__ WhB,
    float* __restrict__ WrT)
{
  const int h = blockIdx.x;    // 0..255
  const int j = threadIdx.x;   // 0..255
  for (int c = j; c < LDWB; c += 256) {
    const float v = (c < NIN) ? Wh[(size_t)h * LDWH + c] : 0.f;
    WhB[(size_t)h * LDWB + c] = f2bf(v);
  }
  WrT[(size_t)j * NH + h] = Wh[(size_t)h * LDWH + NIN + j];
}

// ---------------------------------------------------------------------------
// GEMM: M=256000 (T*B), K=700, N=256.  A=x (f32, K-contig, convert in-flight),
// B=WhB (bf16, K-contig). Tile BM=128 x BN=256 x BK=32, 4 waves (2m x 2n),
// per-wave 64x128 out = 4x8 fragments of 16x16x32.
// ---------------------------------------------------------------------------
#define BM 128
#define BN 256
#define BK 32
#define LDS_STRIDE 40   // bf16 elems per LDS row (padded from 32; 80B rows)

__global__ __launch_bounds__(256) void gemm_xw_kernel(
    const float* __restrict__ X, const unsigned short* __restrict__ WhB,
    unsigned short* __restrict__ Xc)
{
  __shared__ unsigned short As[2][BM][LDS_STRIDE];
  __shared__ unsigned short Bs[2][BN][LDS_STRIDE];

  const int tid  = threadIdx.x;
  const int lane = tid & 63;
  const int wid  = tid >> 6;
  const int wm   = wid & 1;
  const int wn   = wid >> 1;
  const long m0  = (long)blockIdx.x * BM;

  f32x4 acc[4][8];
#pragma unroll
  for (int i = 0; i < 4; i++)
#pragma unroll
    for (int j = 0; j < 8; j++) acc[i][j] = (f32x4){0.f, 0.f, 0.f, 0.f};

  const int arow = tid >> 1, aseg = tid & 1;

  auto stage = [&](int buf, int kt) {
    const int k0 = kt * BK;
    { // A tile: row arow, 16 cols at k0 + aseg*16, f32 -> bf16
      const float* src = X + (m0 + arow) * (long)NIN + k0 + aseg * 16;
      unsigned short tmp[16];
      if (k0 + aseg * 16 + 16 <= NIN) {
#pragma unroll
        for (int c = 0; c < 16; c += 4) {
          float4 v = *reinterpret_cast<const float4*>(src + c);
          tmp[c+0]=f2bf(v.x); tmp[c+1]=f2bf(v.y); tmp[c+2]=f2bf(v.z); tmp[c+3]=f2bf(v.w);
        }
      } else {
#pragma unroll
        for (int c = 0; c < 16; c++) {
          int k = k0 + aseg * 16 + c;
          tmp[c] = (k < NIN) ? f2bf(src[c]) : (unsigned short)0;
        }
      }
      unsigned short* dst = &As[buf][arow][aseg * 16];
      *reinterpret_cast<short8v*>(dst)     = *reinterpret_cast<short8v*>(&tmp[0]);
      *reinterpret_cast<short8v*>(dst + 8) = *reinterpret_cast<short8v*>(&tmp[8]);
    }
    { // B tile: row tid (=h), 32 bf16 at k0 — pure copy (LDWB=704=22*32, padded)
      const unsigned short* src = WhB + (size_t)tid * LDWB + k0;
      unsigned short* dst = &Bs[buf][tid][0];
#pragma unroll
      for (int c = 0; c < 32; c += 8)
        *reinterpret_cast<short8v*>(dst + c) = *reinterpret_cast<const short8v*>(src + c);
    }
  };

  const int fr = lane & 15;
  const int ko = (lane >> 4) * 8;

  auto compute = [&](int buf) {
    short8v af[4], bfv[8];
#pragma unroll
    for (int i = 0; i < 4; i++)
      af[i] = *reinterpret_cast<const short8v*>(&As[buf][wm * 64 + i * 16 + fr][ko]);
#pragma unroll
    for (int j = 0; j < 8; j++)
      bfv[j] = *reinterpret_cast<const short8v*>(&Bs[buf][wn * 128 + j * 16 + fr][ko]);
#pragma unroll
    for (int i = 0; i < 4; i++)
#pragma unroll
      for (int j = 0; j < 8; j++)
        acc[i][j] = __builtin_amdgcn_mfma_f32_16x16x32_bf16(af[i], bfv[j], acc[i][j], 0, 0, 0);
  };

  const int NKT = LDWB / BK;  // 22
  stage(0, 0);
  __syncthreads();
  for (int kt = 0; kt < NKT; kt++) {
    const int buf = kt & 1;
    if (kt + 1 < NKT) stage(buf ^ 1, kt + 1);   // issue stage before compute
    compute(buf);
    __syncthreads();
  }

  // epilogue: C/D layout col=lane&15, row=(lane>>4)*4+reg  [m89-verified]
  const int crow = (lane >> 4) * 4;
#pragma unroll
  for (int i = 0; i < 4; i++) {
#pragma unroll
    for (int j = 0; j < 8; j++) {
      const long mrow = m0 + wm * 64 + i * 16 + crow;
      const int  col  = wn * 128 + j * 16 + fr;
#pragma unroll
      for (int r = 0; r < 4; r++)
        Xc[(mrow + r) * (long)NH + col] = f2bf(acc[i][j][r]);
    }
  }
}

// ---------------------------------------------------------------------------
// Scan: 1 wave per batch, lane handles units h = 4*lane + g (g=0..3).
// Spike exchange is 4 in-register ballots; mask bit l of ballot g <-> h=4l+g.
// No LDS, no barriers. 8-deep ushort4 prefetch ring for Xc.
// ---------------------------------------------------------------------------
#define RING 8

__global__ __launch_bounds__(64) void scan_kernel(
    const unsigned short* __restrict__ Xc,
    const float* __restrict__ WrT,
    const float* __restrict__ Wo,
    const float* __restrict__ tau,
    const float* __restrict__ omega,
    const float* __restrict__ boffset,
    float* __restrict__ out_outputs,
    float* __restrict__ out_zf,
    float* __restrict__ out_uf,
    float* __restrict__ out_ouf)
{
  const int b    = blockIdx.x;
  const int lane = threadIdx.x;      // 0..63
  const int h0   = lane << 2;        // first of this lane's 4 units

  float om[4], bco[4];
#pragma unroll
  for (int g = 0; g < 4; g++) {
    const float o   = fabsf(omega[h0 + g]);
    const float dom = 0.01f * o;
    om[g]  = o;
    // p(omega) - |b_offset|;  b = bco - q
    bco[g] = (-1.f + sqrtf(1.f - dom * dom)) * 100.f - fabsf(boffset[h0 + g]);
  }
  float u[4] = {0.f,0.f,0.f,0.f}, v[4] = {0.f,0.f,0.f,0.f};
  float q[4] = {0.f,0.f,0.f,0.f}, zl[4] = {0.f,0.f,0.f,0.f};
  float ou = 0.f, alpha = 0.f, oma = 0.f;
  if (lane < NOUT) {
    alpha = expf(-0.01f / tau[lane]);
    oma   = 1.f - alpha;
  }

  unsigned long long m0 = 0ULL, m1 = 0ULL, m2 = 0ULL, m3 = 0ULL; // z_{t-1} masks

  const size_t base = (size_t)b * NH + h0;
  ushort4 cb[RING];
#pragma unroll
  for (int i = 0; i < RING; i++)
    cb[i] = *reinterpret_cast<const ushort4*>(Xc + (size_t)i * (BATCH * NH) + base);

  size_t ooff = (size_t)b * NOUT + lane;   // outputs[(t*B+b)*O + lane]

  for (int t0 = 0; t0 < T_STEPS; t0 += RING) {
#pragma unroll
    for (int tt = 0; tt < RING; tt++) {
      const int t = t0 + tt;
      const ushort4 cw = cb[tt];
      if (t + RING < T_STEPS)   // static ring slot (rule #20)
        cb[tt] = *reinterpret_cast<const ushort4*>(
            Xc + (size_t)(t + RING) * (BATCH * NH) + base);

      float cur[4] = { bf2f(cw.x), bf2f(cw.y), bf2f(cw.z), bf2f(cw.w) };

      // recurrent input from z_{t-1} (wave-uniform masks -> uniform branch)
      const int nprev = __popcll(m0) + __popcll(m1) + __popcll(m2) + __popcll(m3);
      if (nprev) {
        unsigned long long m;
        m = m0; while (m) { const int j = (__builtin_ctzll(m) << 2) + 0; m &= m - 1;
          const float4 w = *reinterpret_cast<const float4*>(WrT + (size_t)j * NH + h0);
          cur[0] += w.x; cur[1] += w.y; cur[2] += w.z; cur[3] += w.w; }
        m = m1; while (m) { const int j = (__builtin_ctzll(m) << 2) + 1; m &= m - 1;
          const float4 w = *reinterpret_cast<const float4*>(WrT + (size_t)j * NH + h0);
          cur[0] += w.x; cur[1] += w.y; cur[2] += w.z; cur[3] += w.w; }
        m = m2; while (m) { const int j = (__builtin_ctzll(m) << 2) + 2; m &= m - 1;
          const float4 w = *reinterpret_cast<const float4*>(WrT + (size_t)j * NH + h0);
          cur[0] += w.x; cur[1] += w.y; cur[2] += w.z; cur[3] += w.w; }
        m = m3; while (m) { const int j = (__builtin_ctzll(m) << 2) + 3; m &= m - 1;
          const float4 w = *reinterpret_cast<const float4*>(WrT + (size_t)j * NH + h0);
          cur[0] += w.x; cur[1] += w.y; cur[2] += w.z; cur[3] += w.w; }
      }

      float sarg[4];
#pragma unroll
      for (int g = 0; g < 4; g++) {
        const float bb = bco[g] - q[g];                       // b with q_{t-1}
        u[g] += 0.01f * (bb * u[g] - om[g] * v[g] + cur[g]);
        v[g] += 0.01f * (om[g] * u[g] + bb * v[g]);           // symplectic: new u
        sarg[g] = u[g] - 1.f - q[g];                          // theta + q_{t-1}
      }
      const unsigned long long n0 = __ballot(sarg[0] > 0.f);
      const unsigned long long n1 = __ballot(sarg[1] > 0.f);
      const unsigned long long n2 = __ballot(sarg[2] > 0.f);
      const unsigned long long n3 = __ballot(sarg[3] > 0.f);
#pragma unroll
      for (int g = 0; g < 4; g++) {
        const float zn = (sarg[g] > 0.f) ? 1.f : 0.f;
        q[g]  = 0.9f * q[g] + zn;
        zl[g] = zn;
      }

      // LI readout with z_t (current step's spikes)
      const int nnew = __popcll(n0) + __popcll(n1) + __popcll(n2) + __popcll(n3);
      float sw = 0.f;
      if (nnew) {
        if (lane < NOUT) {
          unsigned long long m;
          m = n0; while (m) { const int j = (__builtin_ctzll(m) << 2) + 0; m &= m - 1; sw += Wo[lane * NH + j]; }
          m = n1; while (m) { const int j = (__builtin_ctzll(m) << 2) + 1; m &= m - 1; sw += Wo[lane * NH + j]; }
          m = n2; while (m) { const int j = (__builtin_ctzll(m) << 2) + 2; m &= m - 1; sw += Wo[lane * NH + j]; }
          m = n3; while (m) { const int j = (__builtin_ctzll(m) << 2) + 3; m &= m - 1; sw += Wo[lane * NH + j]; }
        }
      }
      ou = alpha * ou + oma * sw;     // lanes >= NOUT carry junk, never stored
      if (lane < NOUT) out_outputs[ooff] = ou;
      ooff += (size_t)BATCH * NOUT;

      m0 = n0; m1 = n1; m2 = n2; m3 = n3;
    }
  }

  float4 uo; uo.x = u[0];  uo.y = u[1];  uo.z = u[2];  uo.w = u[3];
  float4 zo; zo.x = zl[0]; zo.y = zl[1]; zo.z = zl[2]; zo.w = zl[3];
  *reinterpret_cast<float4*>(out_uf + (size_t)b * NH + h0) = uo;
  *reinterpret_cast<float4*>(out_zf + (size_t)b * NH + h0) = zo;
  if (lane < NOUT) out_ouf[(size_t)b * NOUT + lane] = ou;
}

// ---------------------------------------------------------------------------
// Loss: block = t (1000), thread = b (256). Per-thread 20-wide log-softmax,
// fully unrolled (static indices -> registers), f64 block reduce -> lossp[t].
// ---------------------------------------------------------------------------
__global__ __launch_bounds__(256) void loss_kernel(
    const float* __restrict__ outputs, const int* __restrict__ y,
    double* __restrict__ lossp)
{
  const int t = blockIdx.x;
  const int b = threadIdx.x;
  const float* o = outputs + ((size_t)t * BATCH + b) * NOUT;

  float vals[NOUT];
#pragma unroll
  for (int i = 0; i < NOUT; i++) vals[i] = o[i];

  float mv = vals[0];
#pragma unroll
  for (int i = 1; i < NOUT; i++) mv = fmaxf(mv, vals[i]);
  float s = 0.f;
#pragma unroll
  for (int i = 0; i < NOUT; i++) s += expf(vals[i] - mv);
  const float lse = mv + logf(s);

  const int yt = y[t * BATCH + b];
  float osel = 0.f;
#pragma unroll
  for (int i = 0; i < NOUT; i++) if (i == yt) osel = vals[i];  // predicated select

  __shared__ double sm[256];
  sm[b] = (double)(lse - osel);
  __syncthreads();
  for (int st = 128; st > 0; st >>= 1) {
    if (b < st) sm[b] += sm[b + st];
    __syncthreads();
  }
  if (b == 0) lossp[t] = sm[0];
}

__global__ __launch_bounds__(256) void loss_reduce_kernel(
    const double* __restrict__ lp, float* __restrict__ out)
{
  const int tid = threadIdx.x;
  double a = 0.0;
  for (int i = tid; i < T_STEPS; i += 256) a += lp[i];
  __shared__ double sm[256];
  sm[tid] = a;
  __syncthreads();
  for (int st = 128; st > 0; st >>= 1) {
    if (tid < st) sm[tid] += sm[tid + st];
    __syncthreads();
  }
  if (tid == 0) out[0] = (float)(sm[0] / (double)BATCH);
}

// ---------------------------------------------------------------------------
extern "C" void kernel_launch(void* const* d_in, const int* in_sizes, int n_in,
                              void* d_out, int out_size, void* d_ws, size_t ws_size,
                              hipStream_t stream)
{
  (void)in_sizes; (void)n_in; (void)out_size; (void)ws_size;

  const float* x     = (const float*)d_in[0];
  const int*   y     = (const int*)  d_in[1];
  const float* Wh    = (const float*)d_in[2];
  const float* omega = (const float*)d_in[3];
  const float* boff  = (const float*)d_in[4];
  const float* Wo    = (const float*)d_in[5];
  const float* tau   = (const float*)d_in[6];
  float* out = (float*)d_out;

  // workspace layout
  const size_t XC_ELEMS = (size_t)T_STEPS * BATCH * NH;            // 65,536,000
  unsigned short* Xc  = (unsigned short*)d_ws;
  unsigned short* WhB = (unsigned short*)((char*)d_ws + XC_ELEMS * sizeof(unsigned short));
  float*  WrT   = (float*) ((char*)WhB + (size_t)NH * LDWB * sizeof(unsigned short));
  double* lossp = (double*)((char*)WrT + (size_t)NH * NH * sizeof(float));

  // output layout: outputs(T,B,O) | loss | zf(B,H) | uf(B,H) | ouf(B,O)
  float* out_outputs = out;
  float* out_loss    = out + (size_t)T_STEPS * BATCH * NOUT;       // 5,120,000
  float* out_zf      = out_loss + 1;
  float* out_uf      = out_zf + (size_t)BATCH * NH;
  float* out_ouf     = out_uf + (size_t)BATCH * NH;

  hipLaunchKernelGGL(prep_kernel, dim3(NH), dim3(256), 0, stream, Wh, WhB, WrT);
  const int M_TILES = (T_STEPS * BATCH) / BM;  // 2000
  hipLaunchKernelGGL(gemm_xw_kernel, dim3(M_TILES), dim3(256), 0, stream, x, WhB, Xc);
  hipLaunchKernelGGL(scan_kernel, dim3(BATCH), dim3(64), 0, stream,
                     Xc, WrT, Wo, tau, omega, boff,
                     out_outputs, out_zf, out_uf, out_ouf);
  hipLaunchKernelGGL(loss_kernel, dim3(T_STEPS), dim3(256), 0, stream,
                     out_outputs, y, lossp);
  hipLaunchKernelGGL(loss_reduce_kernel, dim3(1), dim3(256), 0, stream, lossp, out_loss);
}